// Round 6
// baseline (124.891 us; speedup 1.0000x reference)
//
#include <hip/hip_runtime.h>
#include <hip/hip_fp16.h>
#include <stdint.h>

// BATCH=4096, LENGTH=128, FEAT=4, RANK=64, 126 mid sites.
#define NSITES 126
#define XPITCH 516                 // xbuf row pitch (floats)
#define VPITCH 68                  // vbuf row pitch (floats)

typedef _Float16 half8_t  __attribute__((ext_vector_type(8)));
typedef float    float4_t __attribute__((ext_vector_type(4)));

// light barrier: LDS-only drain; asm G-loads (vmcnt) stay in flight across it
#define LBAR() asm volatile("s_waitcnt lgkmcnt(0)\n\ts_barrier" ::: "memory")
// explicit wait: oldest loads complete when <=N remain outstanding
#define WAITV(N) asm volatile("s_waitcnt vmcnt(" #N ")" ::: "memory")
// zero-instruction tie: pins the 8 frag values behind the preceding WAITV
#define TIE8(F) asm volatile("" : "+v"(F[0]), "+v"(F[1]), "+v"(F[2]), "+v"(F[3]), \
                                  "+v"(F[4]), "+v"(F[5]), "+v"(F[6]), "+v"(F[7]))

// volatile asm load: compiler cannot sink/remat this
__device__ __forceinline__ void aload(half8_t& d, const void* p) {
    asm volatile("global_load_dwordx4 %0, %1, off" : "=v"(d) : "v"(p));
}

// ---------------------------------------------------------------------------
// Repack mid_cores fp32 [126][64][256] -> fp16 B-fragments in exact lane
// order: frag F = ((i*2+h)*4 + w)*64 + lane, 16B each; element j of frag =
// G[l = 32h + 8q + j][n = i*64 + w*16 + c]  (lane = q*16+c).  (unchanged)
// ---------------------------------------------------------------------------
__global__ __launch_bounds__(256) void repack_g(const float* __restrict__ mid,
                                                _Float16* __restrict__ gt) {
    __shared__ float lds[64 * 260];
    const int s = blockIdx.x;
    const int t = threadIdx.x;
    const float* src = mid + (size_t)s * 16384;
#pragma unroll
    for (int k = 0; k < 16; ++k) {
        const int f4 = t + 256 * k;              // float4 index 0..4095
        const int l = f4 >> 6, n0 = (f4 & 63) * 4;
        *(float4_t*)&lds[l * 260 + n0] = *(const float4_t*)&src[f4 * 4];
    }
    __syncthreads();
    half8_t* dst = (half8_t*)gt + (size_t)s * 2048;
#pragma unroll
    for (int m = 0; m < 8; ++m) {
        const int F = t + 256 * m;               // 0..2047
        const int lane = F & 63, w = (F >> 6) & 3, h = (F >> 8) & 1, i = F >> 9;
        const int q = lane >> 4, c = lane & 15;
        const int n = i * 64 + w * 16 + c;
        half8_t o;
#pragma unroll
        for (int j = 0; j < 8; ++j)
            o[j] = (_Float16)lds[(32 * h + 8 * q + j) * 260 + n];
        dst[F] = o;
    }
}

// ---------------------------------------------------------------------------
// Main chain: 256 blocks x 256 threads (1 block/CU, 16 batches, 4 waves on
// 4 SIMDs; wave w owns v'-cols [16w,16w+16)). x is FOLDED into the MFMA A
// operand (K=256: A[b][k=64i+l] = fp16(v_l)*fp16(x_i)), so per site each
// wave does: 4 v-read b128 + 1 x-read b128 (broadcast) + 8 MFMA + 4 writes.
// G streams from L2 via volatile-asm loads, 2-site prefetch, vmcnt(16).
// ---------------------------------------------------------------------------
__global__ __launch_bounds__(256) void tt_chain(
    const float* __restrict__ x,      // [4096][128][4]
    const float* __restrict__ first,  // [4][64]
    const float* __restrict__ last,   // [64][4]
    const _Float16* __restrict__ gt,  // frag-ordered fp16, 32 KB/site
    float* __restrict__ out) {        // [4096]

    __shared__ float vbuf[2][16 * VPITCH];
    __shared__ float xbuf[16 * XPITCH];
    __shared__ int   eacc[16];

    const int tid  = threadIdx.x;
    const int w    = tid >> 6;
    const int lane = tid & 63;
    const int q    = lane >> 4;
    const int c    = lane & 15;
    const int b0   = blockIdx.x * 16;

    // stage x: 16 rows x 512 floats, coalesced
    {
        const int bb = tid >> 4, seg = tid & 15;
        const float4_t* src = (const float4_t*)(x + (size_t)(b0 + bb) * 512 + seg * 32);
        float4_t* dst = (float4_t*)(xbuf + bb * XPITCH + seg * 32);
#pragma unroll
        for (int k = 0; k < 8; ++k) dst[k] = src[k];
    }
    if (tid < 16) eacc[tid] = 0;
    __syncthreads();

    // v0[b,r] = sum_i x[b,0,i] * first[i,r]
    {
        const int bb = tid >> 4, rq = tid & 15;
        const float xs0 = xbuf[bb * XPITCH + 0], xs1 = xbuf[bb * XPITCH + 1];
        const float xs2 = xbuf[bb * XPITCH + 2], xs3 = xbuf[bb * XPITCH + 3];
#pragma unroll
        for (int k = 0; k < 4; ++k) {
            const int r = rq * 4 + k;
            vbuf[0][bb * VPITCH + r] =
                xs0 * first[r] + xs1 * first[64 + r] + xs2 * first[128 + r] + xs3 * first[192 + r];
        }
    }

    // G register pipeline: per wave 8 frags/site (F[2i+h]) at byte offset
    // s*32768 + (2i+h)*4096 + w*1024 + lane*16
    half8_t F0[8], F1[8], F2[8];
    const char* gbase = (const char*)gt + w * 1024 + lane * 16;
    auto LOAD = [&](int s, half8_t* F) {
        const char* p = gbase + (size_t)s * 32768;
#pragma unroll
        for (int ih = 0; ih < 8; ++ih) aload(F[ih], p + ih * 4096);
    };
    LOAD(0, F0);    // outstanding: 8
    LOAD(1, F1);    // outstanding: 16
    LBAR();         // vbuf[0] visible (lgkm only; G loads stay in flight)

    auto STEP = [&](int s, half8_t* F) {
        const int p = s & 1;
        // lane's own batch-c x for site s+1 (broadcast across q-groups)
        const float4_t xv = *(const float4_t*)(xbuf + c * XPITCH + (s + 1) * 4);

        const float* vr = &vbuf[p][c * VPITCH];
        float4_t a0lo = *(const float4_t*)(vr + q * 8);
        float4_t a0hi = *(const float4_t*)(vr + q * 8 + 4);
        float4_t a1lo = *(const float4_t*)(vr + 32 + q * 8);
        float4_t a1hi = *(const float4_t*)(vr + 32 + q * 8 + 4);

        // wave-local per-batch power-of-2 renorm every 8 sites
        if ((s & 7) == 0 && s != 0) {
            float m = 0.f;
#pragma unroll
            for (int k = 0; k < 4; ++k) {
                m = fmaxf(m, fabsf(a0lo[k])); m = fmaxf(m, fabsf(a0hi[k]));
                m = fmaxf(m, fabsf(a1lo[k])); m = fmaxf(m, fabsf(a1hi[k]));
            }
            m = fmaxf(m, __shfl_xor(m, 16));
            m = fmaxf(m, __shfl_xor(m, 32));
            int e = 0;
            if (m > 0.f) frexpf(m, &e);
            const float sc = ldexpf(1.0f, -e);
#pragma unroll
            for (int k = 0; k < 4; ++k) {
                a0lo[k] *= sc; a0hi[k] *= sc; a1lo[k] *= sc; a1hi[k] *= sc;
            }
            if (tid < 16) eacc[tid] += e;   // wave 0, q=0: lane==c==batch
        }

        // vh0[j]=fp16(v[8q+j]), vh1[j]=fp16(v[32+8q+j]); fp16 x (RTN)
        half8_t vh0, vh1;
#pragma unroll
        for (int k = 0; k < 4; ++k) {
            vh0[k] = (_Float16)a0lo[k]; vh0[4 + k] = (_Float16)a0hi[k];
            vh1[k] = (_Float16)a1lo[k]; vh1[4 + k] = (_Float16)a1hi[k];
        }
        const _Float16 xh[4] = { (_Float16)xv.x, (_Float16)xv.y,
                                 (_Float16)xv.z, (_Float16)xv.w };

        WAITV(16);      // this site's 8 G-frags landed (2-site pipeline)
        TIE8(F);

        // two K=128 chains (h=0 / h=1), x folded into A per i-step
        float4_t accE = {0.f, 0.f, 0.f, 0.f};
        float4_t accO = {0.f, 0.f, 0.f, 0.f};
#pragma unroll
        for (int i = 0; i < 4; ++i) {
            half8_t sp;
#pragma unroll
            for (int j = 0; j < 8; ++j) sp[j] = xh[i];
            accE = __builtin_amdgcn_mfma_f32_16x16x32_f16(vh0 * sp, F[2 * i],     accE, 0, 0, 0);
            accO = __builtin_amdgcn_mfma_f32_16x16x32_f16(vh1 * sp, F[2 * i + 1], accO, 0, 0, 0);
        }
        const float4_t acc = accE + accO;   // D = v_{s+1}[b=4q+jj][w*16+c]

#pragma unroll
        for (int jj = 0; jj < 4; ++jj)
            vbuf[p ^ 1][(q * 4 + jj) * VPITCH + w * 16 + c] = acc[jj];
        LBAR();
    };

    for (int s = 0; s < NSITES; s += 3) {
        const int s2 = (s + 2 < NSITES) ? s + 2 : NSITES - 1;
        const int s3 = (s + 3 < NSITES) ? s + 3 : NSITES - 1;
        const int s4 = (s + 4 < NSITES) ? s + 4 : NSITES - 1;
        LOAD(s2, F2);          // every STEP is preceded by exactly one 8-load
        STEP(s, F0);           // LOAD -> WAITV(16) invariant holds throughout
        LOAD(s3, F0);
        STEP(s + 1, F1);
        LOAD(s4, F1);
        STEP(s + 2, F2);
    }
    WAITV(0);   // drain tail (clamped re-loads of site 125)

    // final v in vbuf[0] (126 even); out[b] = 2^eacc * sum_r v*last_vec
    {
        const int bb = tid >> 4, rq = tid & 15;
        const float x0 = xbuf[bb * XPITCH + 508], x1 = xbuf[bb * XPITCH + 509];
        const float x2 = xbuf[bb * XPITCH + 510], x3 = xbuf[bb * XPITCH + 511];
        float dot = 0.f;
#pragma unroll
        for (int k = 0; k < 4; ++k) {
            const int r = rq * 4 + k;
            const float lv = last[r * 4 + 0] * x0 + last[r * 4 + 1] * x1 +
                             last[r * 4 + 2] * x2 + last[r * 4 + 3] * x3;
            dot += lv * vbuf[0][bb * VPITCH + r];
        }
#pragma unroll
        for (int o = 8; o > 0; o >>= 1) dot += __shfl_xor(dot, o, 16);
        if (rq == 0) out[b0 + bb] = ldexpf(dot, eacc[bb]);
    }
}

extern "C" void kernel_launch(void* const* d_in, const int* in_sizes, int n_in,
                              void* d_out, int out_size, void* d_ws, size_t ws_size,
                              hipStream_t stream) {
    (void)in_sizes; (void)n_in; (void)out_size; (void)ws_size;
    const float* x     = (const float*)d_in[0];
    const float* first = (const float*)d_in[1];
    const float* mid   = (const float*)d_in[2];
    const float* last  = (const float*)d_in[3];
    float* out = (float*)d_out;
    _Float16* gt = (_Float16*)d_ws;   // 126*2048*16 B = 4,128,768 B

    repack_g<<<126, 256, 0, stream>>>(mid, gt);
    tt_chain<<<256, 256, 0, stream>>>(x, first, last, gt, out);
}

// Round 7
// 124.336 us; speedup vs baseline: 1.0045x; 1.0045x over previous
//
#include <hip/hip_runtime.h>
#include <hip/hip_fp16.h>
#include <stdint.h>

// BATCH=4096, LENGTH=128, FEAT=4, RANK=64, 126 mid sites.
#define NSITES 126
#define XPITCH 516                 // xbuf row pitch (floats)
#define VPITCH 68                  // vbuf row pitch (floats)

typedef _Float16 half8_t  __attribute__((ext_vector_type(8)));
typedef float    float4_t __attribute__((ext_vector_type(4)));

// light barrier: LDS-only drain; asm G-loads (vmcnt) stay in flight across it
#define LBAR() asm volatile("s_waitcnt lgkmcnt(0)\n\ts_barrier" ::: "memory")
// explicit wait: oldest loads complete when <=N remain outstanding
#define WAITV(N) asm volatile("s_waitcnt vmcnt(" #N ")" ::: "memory")
// zero-instruction tie: pins the 8 frag values behind the preceding WAITV
#define TIE8(F) asm volatile("" : "+v"(F[0]), "+v"(F[1]), "+v"(F[2]), "+v"(F[3]), \
                                  "+v"(F[4]), "+v"(F[5]), "+v"(F[6]), "+v"(F[7]))

// volatile asm load, SGPR base + VGPR offset: no per-load VALU addressing,
// and the compiler cannot sink/remat it (R3 lesson).
__device__ __forceinline__ void aload(half8_t& d, uint32_t voff, uint64_t sbase) {
    asm volatile("global_load_dwordx4 %0, %1, %2 offset:0"
                 : "=v"(d) : "v"(voff), "s"(sbase));
}

// ---------------------------------------------------------------------------
// Repack mid_cores fp32 [126][64][256] -> fp16 B-fragments in exact lane
// order: frag F = ((i*2+h)*4 + w)*64 + lane, 16B each; element j of frag =
// G[l = 32h + 8q + j][n = i*64 + w*16 + c]  (lane = q*16+c).  (unchanged)
// ---------------------------------------------------------------------------
__global__ __launch_bounds__(256) void repack_g(const float* __restrict__ mid,
                                                _Float16* __restrict__ gt) {
    __shared__ float lds[64 * 260];
    const int s = blockIdx.x;
    const int t = threadIdx.x;
    const float* src = mid + (size_t)s * 16384;
#pragma unroll
    for (int k = 0; k < 16; ++k) {
        const int f4 = t + 256 * k;              // float4 index 0..4095
        const int l = f4 >> 6, n0 = (f4 & 63) * 4;
        *(float4_t*)&lds[l * 260 + n0] = *(const float4_t*)&src[f4 * 4];
    }
    __syncthreads();
    half8_t* dst = (half8_t*)gt + (size_t)s * 2048;
#pragma unroll
    for (int m = 0; m < 8; ++m) {
        const int F = t + 256 * m;               // 0..2047
        const int lane = F & 63, w = (F >> 6) & 3, h = (F >> 8) & 1, i = F >> 9;
        const int q = lane >> 4, c = lane & 15;
        const int n = i * 64 + w * 16 + c;
        half8_t o;
#pragma unroll
        for (int j = 0; j < 8; ++j)
            o[j] = (_Float16)lds[(32 * h + 8 * q + j) * 260 + n];
        dst[F] = o;
    }
}

// ---------------------------------------------------------------------------
// Main chain: 256 blocks x 256 threads (1 block/CU, 16 batches, 4 waves).
// R5 structure. NEW: per-XCD site-phase stagger — same-XCD CUs otherwise
// read the SAME 32KB G-lines in lock-step (barrier rhythm), and L2
// serializes same-line service, halving effective BW (measured 1160
// cyc/site ~= 2x the 585-cyc XCD-L2 floor). Stagger spreads the 32 CUs of
// an XCD over 8 site-phases so they request different lines at any instant.
// ---------------------------------------------------------------------------
__global__ __launch_bounds__(256) void tt_chain(
    const float* __restrict__ x,      // [4096][128][4]
    const float* __restrict__ first,  // [4][64]
    const float* __restrict__ last,   // [64][4]
    const _Float16* __restrict__ gt,  // frag-ordered fp16, 32 KB/site
    float* __restrict__ out) {        // [4096]

    __shared__ float vbuf[2][16 * VPITCH];
    __shared__ float xbuf[16 * XPITCH];
    __shared__ int   eacc[16];

    const int tid  = threadIdx.x;
    const int w    = tid >> 6;
    const int lane = tid & 63;
    const int q    = lane >> 4;
    const int c    = lane & 15;
    const int b0   = blockIdx.x * 16;

    // ---- site-phase stagger: XCD = blockIdx%8 on MI355X, so same-XCD
    // blocks differ in bits >=3. 8 phases x ~960 cyc ~= 1 site-time apart.
    {
        const int phase = (blockIdx.x >> 3) & 7;
        for (int d = 0; d < phase; ++d) asm volatile("s_sleep 15");
    }

    // stage x: 16 rows x 512 floats, coalesced
    {
        const int bb = tid >> 4, seg = tid & 15;
        const float4_t* src = (const float4_t*)(x + (size_t)(b0 + bb) * 512 + seg * 32);
        float4_t* dst = (float4_t*)(xbuf + bb * XPITCH + seg * 32);
#pragma unroll
        for (int k = 0; k < 8; ++k) dst[k] = src[k];
    }
    if (tid < 16) eacc[tid] = 0;
    __syncthreads();

    // v0[b,r] = sum_i x[b,0,i] * first[i,r]
    {
        const int bb = tid >> 4, rq = tid & 15;
        const float xs0 = xbuf[bb * XPITCH + 0], xs1 = xbuf[bb * XPITCH + 1];
        const float xs2 = xbuf[bb * XPITCH + 2], xs3 = xbuf[bb * XPITCH + 3];
#pragma unroll
        for (int k = 0; k < 4; ++k) {
            const int r = rq * 4 + k;
            vbuf[0][bb * VPITCH + r] =
                xs0 * first[r] + xs1 * first[64 + r] + xs2 * first[128 + r] + xs3 * first[192 + r];
        }
    }

    // G register pipeline: per wave 8 frags/site; VGPR offsets fixed,
    // SGPR base advances per site (zero VALU addressing in the loop).
    half8_t F0[8], F1[8], F2[8];
    uint32_t voff[8];
#pragma unroll
    for (int ih = 0; ih < 8; ++ih) voff[ih] = ih * 4096 + w * 1024 + lane * 16;
    auto LOAD = [&](int s, half8_t* F) {
        const uint64_t sb = (uint64_t)gt + (uint32_t)s * 32768u;
#pragma unroll
        for (int ih = 0; ih < 8; ++ih) aload(F[ih], voff[ih], sb);
    };
    LOAD(0, F0);    // outstanding: 8
    LOAD(1, F1);    // outstanding: 16
    LBAR();         // vbuf[0] visible (lgkm only; G loads stay in flight)

    auto STEP = [&](int s, half8_t* F) {
        const int p = s & 1;
        const float* vr = &vbuf[p][c * VPITCH];
        float4_t a0lo = *(const float4_t*)(vr + q * 8);
        float4_t a0hi = *(const float4_t*)(vr + q * 8 + 4);
        float4_t a1lo = *(const float4_t*)(vr + 32 + q * 8);
        float4_t a1hi = *(const float4_t*)(vr + 32 + q * 8 + 4);

        // wave-local per-batch power-of-2 renorm every 8 sites
        if ((s & 7) == 0 && s != 0) {
            float m = 0.f;
#pragma unroll
            for (int k = 0; k < 4; ++k) {
                m = fmaxf(m, fabsf(a0lo[k])); m = fmaxf(m, fabsf(a0hi[k]));
                m = fmaxf(m, fabsf(a1lo[k])); m = fmaxf(m, fabsf(a1hi[k]));
            }
            m = fmaxf(m, __shfl_xor(m, 16));
            m = fmaxf(m, __shfl_xor(m, 32));
            int e = 0;
            if (m > 0.f) frexpf(m, &e);
            const float sc = ldexpf(1.0f, -e);
#pragma unroll
            for (int k = 0; k < 4; ++k) {
                a0lo[k] *= sc; a0hi[k] *= sc; a1lo[k] *= sc; a1hi[k] *= sc;
            }
            if (tid < 16) eacc[tid] += e;   // wave 0, q=0: lane==c==batch
        }

        half8_t af0, af1;
#pragma unroll
        for (int k = 0; k < 4; ++k) {
            af0[k] = (_Float16)a0lo[k]; af0[4 + k] = (_Float16)a0hi[k];
            af1[k] = (_Float16)a1lo[k]; af1[4 + k] = (_Float16)a1hi[k];
        }

        float4_t xs[4];
#pragma unroll
        for (int jj = 0; jj < 4; ++jj)
            xs[jj] = *(const float4_t*)(xbuf + (q * 4 + jj) * XPITCH + (s + 1) * 4);

        // G-wait placed AFTER the v-read+cast: ds_read latency (~120 cyc)
        // overlaps the residual vmcnt wait.
        WAITV(16);
        TIE8(F);

        float4_t acc[4];
#pragma unroll
        for (int i = 0; i < 4; ++i) {
            float4_t z = {0.f, 0.f, 0.f, 0.f};
            z = __builtin_amdgcn_mfma_f32_16x16x32_f16(af0, F[i * 2 + 0], z, 0, 0, 0);
            z = __builtin_amdgcn_mfma_f32_16x16x32_f16(af1, F[i * 2 + 1], z, 0, 0, 0);
            acc[i] = z;
        }

#pragma unroll
        for (int jj = 0; jj < 4; ++jj) {
            const float vn = xs[jj].x * acc[0][jj] + xs[jj].y * acc[1][jj] +
                             xs[jj].z * acc[2][jj] + xs[jj].w * acc[3][jj];
            vbuf[p ^ 1][(q * 4 + jj) * VPITCH + w * 16 + c] = vn;
        }
        LBAR();
    };

    for (int s = 0; s < NSITES; s += 3) {
        const int s2 = (s + 2 < NSITES) ? s + 2 : NSITES - 1;
        const int s3 = (s + 3 < NSITES) ? s + 3 : NSITES - 1;
        const int s4 = (s + 4 < NSITES) ? s + 4 : NSITES - 1;
        LOAD(s2, F2);          // every STEP is preceded by exactly one 8-load
        STEP(s, F0);           // LOAD -> WAITV(16) invariant holds throughout
        LOAD(s3, F0);
        STEP(s + 1, F1);
        LOAD(s4, F1);
        STEP(s + 2, F2);
    }
    WAITV(0);   // drain tail (clamped re-loads of site 125)

    // final v in vbuf[0] (126 even); out[b] = 2^eacc * sum_r v*last_vec
    {
        const int bb = tid >> 4, rq = tid & 15;
        const float x0 = xbuf[bb * XPITCH + 508], x1 = xbuf[bb * XPITCH + 509];
        const float x2 = xbuf[bb * XPITCH + 510], x3 = xbuf[bb * XPITCH + 511];
        float dot = 0.f;
#pragma unroll
        for (int k = 0; k < 4; ++k) {
            const int r = rq * 4 + k;
            const float lv = last[r * 4 + 0] * x0 + last[r * 4 + 1] * x1 +
                             last[r * 4 + 2] * x2 + last[r * 4 + 3] * x3;
            dot += lv * vbuf[0][bb * VPITCH + r];
        }
#pragma unroll
        for (int o = 8; o > 0; o >>= 1) dot += __shfl_xor(dot, o, 16);
        if (rq == 0) out[b0 + bb] = ldexpf(dot, eacc[bb]);
    }
}

extern "C" void kernel_launch(void* const* d_in, const int* in_sizes, int n_in,
                              void* d_out, int out_size, void* d_ws, size_t ws_size,
                              hipStream_t stream) {
    (void)in_sizes; (void)n_in; (void)out_size; (void)ws_size;
    const float* x     = (const float*)d_in[0];
    const float* first = (const float*)d_in[1];
    const float* mid   = (const float*)d_in[2];
    const float* last  = (const float*)d_in[3];
    float* out = (float*)d_out;
    _Float16* gt = (_Float16*)d_ws;   // 126*2048*16 B = 4,128,768 B

    repack_g<<<126, 256, 0, stream>>>(mid, gt);
    tt_chain<<<256, 256, 0, stream>>>(x, first, last, gt, out);
}